// Round 13
// baseline (611.920 us; speedup 1.0000x reference)
//
#include <hip/hip_runtime.h>
#include <math.h>

// Problem constants
#define EXPERTS 8
#define DDIM 2048
#define HDIM 2048
#define NTOK 4096
#define NPAIR 8192
#define MAXSLOT 9216    // 8192 + 8*127 rounded up (128-padded per expert)
#define MAXTILE 72      // max sum of ceil(cnt_e/128)

typedef _Float16 f16;
typedef __attribute__((ext_vector_type(8))) _Float16 f16x8;
typedef __attribute__((ext_vector_type(4))) _Float16 f16x4;
typedef __attribute__((ext_vector_type(4))) float f32x4;

// ---- workspace layout (bytes); peak ~92 MB (no weight transposes) ----
#define XF_OFF   0ull                 // f16 [NTOK][2048]    = 16MB
#define ACT_OFF  16777216ull          // f16 [MAXSLOT][2048] = 37.75MB
#define Y_OFF    54525952ull          // f16 [MAXSLOT][2048] = 37.75MB
#define CTRL_OFF 92274688ull
// ctrl ints: slot_tok[9216]@0, tok_slot[8192]@9216, cnt[8]@17408,
// cursor[8]@17416, tile_e[72]@17424, tile_r0[72]@17496, n_tiles@17568,
// is32@17569, slot_w(float)[9216]@17576
#define CTRL_INTS 26792

#define BARRIER() asm volatile("s_barrier" ::: "memory")
#define VMCNT(n)  asm volatile("s_waitcnt vmcnt(" #n ")" ::: "memory")
#define LGKM0()   asm volatile("s_waitcnt lgkmcnt(0)" ::: "memory")

__device__ __forceinline__ void gload_lds16(const void* g, void* l) {
  __builtin_amdgcn_global_load_lds(
      (const __attribute__((address_space(1))) unsigned int*)g,
      (__attribute__((address_space(3))) unsigned int*)l,
      16, 0, 0);
}

// ---------------- routing ----------------
__global__ void k_detect(const int* __restrict__ w, int* flag) {
  int i = blockIdx.x * blockDim.x + threadIdx.x;
  if (i < NPAIR / 2 && w[2 * i + 1] != 0) atomicOr(flag, 1);
}

__device__ __forceinline__ int expert_of(const int* idx, int is32, int p) {
  return is32 ? idx[p] : idx[2 * p];
}

__global__ void k_count(const int* __restrict__ idx, const int* __restrict__ flag,
                        int* cnt) {
  int p = blockIdx.x * blockDim.x + threadIdx.x;
  if (p < NPAIR) atomicAdd(&cnt[expert_of(idx, *flag, p)], 1);
}

__global__ void k_plan(const int* __restrict__ cnt, int* cursor,
                       int* tile_e, int* tile_r0, int* n_tiles) {
  if (blockIdx.x == 0 && threadIdx.x == 0) {
    int off = 0, nt = 0;
    for (int e = 0; e < EXPERTS; ++e) {
      cursor[e] = off;
      int t = (cnt[e] + 127) >> 7;
      for (int i = 0; i < t; ++i) { tile_e[nt] = e; tile_r0[nt] = off + i * 128; ++nt; }
      off += t * 128;
    }
    *n_tiles = nt;
  }
}

__global__ void k_assign(const int* __restrict__ idx, const int* __restrict__ flag,
                         const float* __restrict__ wts, const float* __restrict__ scale,
                         int* cursor, int* slot_tok, int* tok_slot, float* slot_w) {
  int p = blockIdx.x * blockDim.x + threadIdx.x;
  if (p < NPAIR) {
    int e = expert_of(idx, *flag, p);
    int pos = atomicAdd(&cursor[e], 1);
    slot_tok[pos] = p >> 1;
    tok_slot[p] = pos;
    slot_w[pos] = wts[p] * scale[e];
  }
}

__global__ void k_cvt_x(const float* __restrict__ in, f16* __restrict__ out) {
  int i = blockIdx.x * blockDim.x + threadIdx.x;
  float4 v = ((const float4*)in)[i];
  f16x4 o = {(f16)v.x, (f16)v.y, (f16)v.z, (f16)v.w};
  ((f16x4*)out)[i] = o;
}

// ----- 128x128x64 grouped GEMM, f32 weights direct, TRUE 2-deep B -----
// 8 waves (2M x 4N), wave-out 64x32, acc[4][2]=32 VGPR, BK=64, double-buffered
// 64KB LDS -> 2 blk/CU (16 waves). B staged f32->regs in TWO parity arrays
// (qe/qo, static via 2x-unrolled loop). Invariant entering kt: outstanding =
// [B(kt+2):8]; B(kt+1) regs LANDED (drained by kt-1's VMCNT(8)); A(kt),B(kt)
// in LDS buf kt&1. Per kt: writeB(Q, s^1) [NO WAIT] -> gloadA(s^1,kt+1) ->
// sched_barrier -> loadB(Q, kt+3) -> compute -> VMCNT(8) [keeps B(kt+3):8,
// drains B(kt+2)+A(kt+1)] -> LGKM0 -> BARRIER. B slack ~2 kt >> L3 latency.
// Dispatch: XCD-grouped nt (same-nt blocks adjacent within an XCD group ->
// B strips L2-resident across ~9 m-tiles).
// G1: A = gathered xf; B = gate_up [2048][4096] (64 gate + 64 up cols);
//     in-wave exact gelu(gate)*up -> act. G0: A = act; B = down -> y.
template <int G1>
__global__ __launch_bounds__(512, 2) void k_gemm(
    const f16* __restrict__ Asrc, const float* __restrict__ W,
    const int* __restrict__ slot_tok,
    const int* __restrict__ tile_e, const int* __restrict__ tile_r0,
    const int* __restrict__ n_tiles, f16* __restrict__ dst) {
  __shared__ __align__(16) f16 smem[2][16384];  // per buf: A[0,8192) B[8192,16384)

  // XCD-grouped remap: group (oid&7) owns an nt-subrange across all m-tiles;
  // within a group, nt cycles fastest -> same-nt blocks ~GP apart (L2-hot).
  const int NTX = G1 ? 32 : 16;
  const int GP = NTX / 8;
  const int oid = (int)(blockIdx.y * NTX + blockIdx.x);
  const int nt = (oid & 7) * GP + ((oid >> 3) & (GP - 1));
  const int bx = oid >> (G1 ? 5 : 4);
  if (bx >= *n_tiles) return;
  const int e = tile_e[bx];
  const int m0 = tile_r0[bx];
  const int LDB = G1 ? 4096 : 2048;

  const int tid = threadIdx.x;
  const int lane = tid & 63;
  const int wv = tid >> 6;
  const int wrM = wv >> 2;   // 0..1 : 64-row band
  const int wcl = wv & 3;    // 0..3 : 16-col tile group
  const int fr = lane & 15;
  const int fhi = lane >> 4;

  // ---- A staging (gload_lds, linear dest, inverse-swz src; R10-proven) ----
  const f16* aS[2];
#pragma unroll
  for (int i = 0; i < 2; ++i) {
    const int r = i * 64 + (tid >> 3);            // tile row 0..127
    size_t arow = G1 ? (size_t)slot_tok[m0 + r] : (size_t)(m0 + r);
    aS[i] = Asrc + arow * 2048 + ((tid & 7) ^ (r & 7)) * 8;
  }
  auto gloadA = [&](int s, int kt) {
#pragma unroll
    for (int i = 0; i < 2; ++i)
      gload_lds16(aS[i] + (size_t)kt * 64, &smem[s][i * 4096 + tid * 8]);
  };

  // ---- B staging: thread covers cols {2cp,2cp+1} x k-octet kf (R10) ----
  const int cp = tid & 63;    // col pair 0..63 (tile cols 0..127)
  const int kf = tid >> 6;    // k-octet 0..7 within BK=64
  int gcol;
  if (G1) gcol = (cp < 32) ? nt * 64 + 2 * cp : 2048 + nt * 64 + (2 * cp - 64);
  else    gcol = nt * 128 + 2 * cp;
  const float* bP = W + (size_t)e * 2048 * LDB + (size_t)(8 * kf) * LDB + gcol;
  const int bbase = 8192 + 2 * cp * 64 + ((kf ^ (cp & 7)) << 3);  // f16 units

  float2 qe[8], qo[8];  // parity reg arrays, constant indices only
  auto loadB = [&](float2 (&q)[8], int kt) {
    const float* p = bP + (size_t)kt * 64 * LDB;
#pragma unroll
    for (int j = 0; j < 8; ++j) q[j] = *(const float2*)(p + j * LDB);
  };
  auto writeB = [&](float2 (&q)[8], int s) {
    f16x8 wa = {(f16)q[0].x, (f16)q[1].x, (f16)q[2].x, (f16)q[3].x,
                (f16)q[4].x, (f16)q[5].x, (f16)q[6].x, (f16)q[7].x};
    f16x8 wb = {(f16)q[0].y, (f16)q[1].y, (f16)q[2].y, (f16)q[3].y,
                (f16)q[4].y, (f16)q[5].y, (f16)q[6].y, (f16)q[7].y};
    *(f16x8*)&smem[s][bbase] = wa;        // col 2cp
    *(f16x8*)&smem[s][bbase + 64] = wb;   // col 2cp+1 (same swz key cp)
  };

  // B-frag col-tiles: ci=0 gate ct=wcl, ci=1 up ct=wcl+4; G0: wcl*2+ci
  int ctv[2];
#pragma unroll
  for (int ci = 0; ci < 2; ++ci)
    ctv[ci] = G1 ? (wcl + ci * 4) : (wcl * 2 + ci);

  f32x4 acc[4][2];
#pragma unroll
  for (int i = 0; i < 4; ++i)
#pragma unroll
    for (int j = 0; j < 2; ++j) acc[i][j] = (f32x4){0.f, 0.f, 0.f, 0.f};

  auto compute = [&](int s) {
    const f16* As = &smem[s][0];
    const f16* Bs = &smem[s][8192];
    f16x8 af[4][2], bf[2][2];
#pragma unroll
    for (int mi = 0; mi < 4; ++mi)
#pragma unroll
      for (int k0 = 0; k0 < 2; ++k0) {
        const int r = wrM * 64 + mi * 16 + fr;
        af[mi][k0] = *(const f16x8*)&As[r * 64 + (((k0 * 4 + fhi) ^ (r & 7)) << 3)];
      }
#pragma unroll
    for (int ci = 0; ci < 2; ++ci)
#pragma unroll
      for (int k0 = 0; k0 < 2; ++k0) {
        const int c = ctv[ci] * 16 + fr;
        bf[ci][k0] = *(const f16x8*)&Bs[c * 64 + (((k0 * 4 + fhi) ^ ((c >> 1) & 7)) << 3)];
      }
    __builtin_amdgcn_s_setprio(1);
#pragma unroll
    for (int k0 = 0; k0 < 2; ++k0)
#pragma unroll
      for (int mi = 0; mi < 4; ++mi)
#pragma unroll
        for (int ci = 0; ci < 2; ++ci)
          acc[mi][ci] = __builtin_amdgcn_mfma_f32_16x16x32_f16(
              af[mi][k0], bf[ci][k0], acc[mi][ci], 0, 0, 0);
    __builtin_amdgcn_s_setprio(0);
  };

  const int NT = 32;  // K / 64

  // ---- prologue (2-deep B) ----
  loadB(qe, 0);      // 8  : B(0)
  loadB(qo, 1);      // 16 : B(1)
  gloadA(0, 0);      // 18
  VMCNT(10);         // B(0) regs landed (keep B(1):8 + A(0):2)
  writeB(qe, 0);
  __builtin_amdgcn_sched_barrier(0);
  loadB(qe, 2);      // outstanding: B(1):8, A(0):2, B(2):8
  VMCNT(8);          // drain B(1) regs + A(0); keep B(2):8
  LGKM0();
  BARRIER();

  // ---- main loop (see header comment for the verified invariant) ----
  auto giter = [&](int kt, float2 (&Q)[8]) {
    const int s = kt & 1;
    if (kt + 1 < NT) {
      writeB(Q, s ^ 1);          // regs landed at kt-1 boundary; NO wait
      gloadA(s ^ 1, kt + 1);     // 2 vm (older than loadB below)
      __builtin_amdgcn_sched_barrier(0);
      if (kt + 3 < NT) loadB(Q, kt + 3);  // 8 vm, same parity array
    }
    compute(s);
    if (kt + 1 < NT) {
      if (kt + 3 < NT) { VMCNT(8); } else { VMCNT(0); }
      LGKM0();
      BARRIER();
    }
  };
  for (int kt = 0; kt < NT; kt += 2) {
    giter(kt, qo);      // B(kt+1) odd parity; loadB(kt+3) odd
    giter(kt + 1, qe);  // B(kt+2) even parity; loadB(kt+4) even
  }

  // ---- epilogue (no LDS) ----
  if (G1) {
#pragma unroll
    for (int mi = 0; mi < 4; ++mi)
#pragma unroll
      for (int rg = 0; rg < 4; ++rg) {
        const int row = m0 + wrM * 64 + mi * 16 + fhi * 4 + rg;
        const int col = nt * 64 + wcl * 16 + fr;
        const float g = acc[mi][0][rg];
        const float u = acc[mi][1][rg];
        const float a = 0.5f * g * (1.0f + erff(g * 0.70710678118654752f)) * u;
        dst[(size_t)row * 2048 + col] = (f16)a;
      }
  } else {
#pragma unroll
    for (int mi = 0; mi < 4; ++mi)
#pragma unroll
      for (int ci = 0; ci < 2; ++ci)
#pragma unroll
        for (int rg = 0; rg < 4; ++rg) {
          const int row = m0 + wrM * 64 + mi * 16 + fhi * 4 + rg;
          const int col = nt * 128 + (wcl * 2 + ci) * 16 + fr;
          dst[(size_t)row * 2048 + col] = (f16)acc[mi][ci][rg];
        }
  }
}

// out[tok] = w(s0)*y[s0] + w(s1)*y[s1]  (fully writes out; no memset needed)
__global__ void k_combine(const f16* __restrict__ y, const float* __restrict__ slot_w,
                          const int* __restrict__ tok_slot, float* __restrict__ out) {
  const int gid = blockIdx.x * blockDim.x + threadIdx.x;
  const int tok = gid >> 8;
  const int c = (gid & 255) * 8;
  const int s0 = tok_slot[2 * tok], s1 = tok_slot[2 * tok + 1];
  const float w0 = slot_w[s0], w1 = slot_w[s1];
  const f16x8 v0 = *(const f16x8*)&y[(size_t)s0 * 2048 + c];
  const f16x8 v1 = *(const f16x8*)&y[(size_t)s1 * 2048 + c];
  float o[8];
#pragma unroll
  for (int j = 0; j < 8; ++j) o[j] = w0 * (float)v0[j] + w1 * (float)v1[j];
  float4* op = (float4*)&out[(size_t)tok * 2048 + c];
  op[0] = (float4){o[0], o[1], o[2], o[3]};
  op[1] = (float4){o[4], o[5], o[6], o[7]};
}

extern "C" void kernel_launch(void* const* d_in, const int* in_sizes, int n_in,
                              void* d_out, int out_size, void* d_ws, size_t ws_size,
                              hipStream_t stream) {
  const float* x = (const float*)d_in[0];
  const float* wts = (const float*)d_in[1];
  const int* idx = (const int*)d_in[2];
  const float* gup = (const float*)d_in[3];
  const float* dwn = (const float*)d_in[4];
  const float* scale = (const float*)d_in[5];
  float* out = (float*)d_out;

  char* ws = (char*)d_ws;
  f16* xf = (f16*)(ws + XF_OFF);
  f16* act = (f16*)(ws + ACT_OFF);
  f16* y = (f16*)(ws + Y_OFF);
  int* ctrl = (int*)(ws + CTRL_OFF);
  int* slot_tok = ctrl;
  int* tok_slot = ctrl + 9216;
  int* cnt = ctrl + 17408;
  int* cursor = ctrl + 17416;
  int* tile_e = ctrl + 17424;
  int* tile_r0 = ctrl + 17496;
  int* n_tiles = ctrl + 17568;
  int* is32 = ctrl + 17569;
  float* slot_w = (float*)(ctrl + 17576);

  hipMemsetAsync(ctrl, 0, (size_t)CTRL_INTS * sizeof(int), stream);

  k_detect<<<NPAIR / 2 / 256, 256, 0, stream>>>(idx, is32);
  k_count<<<NPAIR / 256, 256, 0, stream>>>(idx, is32, cnt);
  k_plan<<<1, 1, 0, stream>>>(cnt, cursor, tile_e, tile_r0, n_tiles);
  k_assign<<<NPAIR / 256, 256, 0, stream>>>(idx, is32, wts, scale, cursor,
                                            slot_tok, tok_slot, slot_w);
  k_cvt_x<<<NTOK * DDIM / 4 / 256, 256, 0, stream>>>(x, xf);
  k_gemm<1><<<dim3(32, MAXTILE), 512, 0, stream>>>(xf, gup, slot_tok, tile_e,
                                                   tile_r0, n_tiles, act);
  k_gemm<0><<<dim3(16, MAXTILE), 512, 0, stream>>>(act, dwn, slot_tok, tile_e,
                                                   tile_r0, n_tiles, y);
  k_combine<<<NTOK, 256, 0, stream>>>(y, slot_w, tok_slot, out);
}

// Round 14
// 482.468 us; speedup vs baseline: 1.2683x; 1.2683x over previous
//
#include <hip/hip_runtime.h>
#include <math.h>

// Problem constants
#define EXPERTS 8
#define DDIM 2048
#define HDIM 2048
#define NTOK 4096
#define NPAIR 8192
#define MAXSLOT 9216    // 8192 + 8*127 rounded up (128-padded per expert)
#define MAXTILE 72      // max sum of ceil(cnt_e/128)

typedef _Float16 f16;
typedef __attribute__((ext_vector_type(8))) _Float16 f16x8;
typedef __attribute__((ext_vector_type(4))) _Float16 f16x4;
typedef __attribute__((ext_vector_type(4))) float f32x4;

// ---- workspace layout (bytes); peak ~193 MB (R2-proven aliasing) ----
// Phase 1: gup_t f16 [E][4096][2048] @0 (128MB)
// Phase 2 (gup_t dead after GEMM1): y @0 (37.75MB), down_t @41.94MB (64MB)
#define GUPT_OFF 0ull
#define Y_OFF    0ull
#define DWNT_OFF 41943040ull
#define XF_OFF   134217728ull    // f16 [NTOK][2048] = 16MB
#define ACT_OFF  150994944ull    // f16 [MAXSLOT][2048] = 37.75MB
#define CTRL_OFF 192937984ull
// ctrl ints: slot_tok[9216]@0, tok_slot[8192]@9216, cnt[8]@17408,
// cursor[8]@17416, tile_e[72]@17424, tile_r0[72]@17496, n_tiles@17568,
// is32@17569, slot_w(float)[9216]@17576
#define CTRL_INTS 26792

#define BARRIER() asm volatile("s_barrier" ::: "memory")
#define VMCNT(n)  asm volatile("s_waitcnt vmcnt(" #n ")" ::: "memory")

__device__ __forceinline__ void gload_lds16(const void* g, void* l) {
  __builtin_amdgcn_global_load_lds(
      (const __attribute__((address_space(1))) unsigned int*)g,
      (__attribute__((address_space(3))) unsigned int*)l,
      16, 0, 0);
}

// ---------------- routing ----------------
__global__ void k_detect(const int* __restrict__ w, int* flag) {
  int i = blockIdx.x * blockDim.x + threadIdx.x;
  if (i < NPAIR / 2 && w[2 * i + 1] != 0) atomicOr(flag, 1);
}

__device__ __forceinline__ int expert_of(const int* idx, int is32, int p) {
  return is32 ? idx[p] : idx[2 * p];
}

__global__ void k_count(const int* __restrict__ idx, const int* __restrict__ flag,
                        int* cnt) {
  int p = blockIdx.x * blockDim.x + threadIdx.x;
  if (p < NPAIR) atomicAdd(&cnt[expert_of(idx, *flag, p)], 1);
}

__global__ void k_plan(const int* __restrict__ cnt, int* cursor,
                       int* tile_e, int* tile_r0, int* n_tiles) {
  if (blockIdx.x == 0 && threadIdx.x == 0) {
    int off = 0, nt = 0;
    for (int e = 0; e < EXPERTS; ++e) {
      cursor[e] = off;
      int t = (cnt[e] + 127) >> 7;
      for (int i = 0; i < t; ++i) { tile_e[nt] = e; tile_r0[nt] = off + i * 128; ++nt; }
      off += t * 128;
    }
    *n_tiles = nt;
  }
}

__global__ void k_assign(const int* __restrict__ idx, const int* __restrict__ flag,
                         const float* __restrict__ wts, const float* __restrict__ scale,
                         int* cursor, int* slot_tok, int* tok_slot, float* slot_w) {
  int p = blockIdx.x * blockDim.x + threadIdx.x;
  if (p < NPAIR) {
    int e = expert_of(idx, *flag, p);
    int pos = atomicAdd(&cursor[e], 1);
    slot_tok[pos] = p >> 1;
    tok_slot[p] = pos;
    slot_w[pos] = wts[p] * scale[e];
  }
}

__global__ void k_cvt_x(const float* __restrict__ in, f16* __restrict__ out) {
  int i = blockIdx.x * blockDim.x + threadIdx.x;
  float4 v = ((const float4*)in)[i];
  f16x4 o = {(f16)v.x, (f16)v.y, (f16)v.z, (f16)v.w};
  ((f16x4*)out)[i] = o;
}

// ---- fast fused cvt+transpose: f32 [R][C] -> f16 [C][R], per expert z ----
__global__ __launch_bounds__(256) void k_transpose(const float* __restrict__ in,
                                                   f16* __restrict__ out,
                                                   int R, int C) {
  __shared__ float t[64][65];
  const size_t base = (size_t)blockIdx.z * R * C;
  const float* ip = in + base;
  f16* op = out + base;
  const int c0 = blockIdx.x * 64, r0 = blockIdx.y * 64;
  const int tid = threadIdx.x;
  const int rr = tid >> 4, cc = (tid & 15) * 4;
#pragma unroll
  for (int i = 0; i < 4; ++i) {
    float4 v = *(const float4*)&ip[(size_t)(r0 + rr + i * 16) * C + c0 + cc];
    *(float4*)&t[rr + i * 16][cc] = v;
  }
  __syncthreads();
  const int k0 = (tid & 7) * 8;
#pragma unroll
  for (int p = 0; p < 2; ++p) {
    const int j = (tid >> 3) + p * 32;
    f16x8 w = {(f16)t[k0 + 0][j], (f16)t[k0 + 1][j], (f16)t[k0 + 2][j],
               (f16)t[k0 + 3][j], (f16)t[k0 + 4][j], (f16)t[k0 + 5][j],
               (f16)t[k0 + 6][j], (f16)t[k0 + 7][j]};
    *(f16x8*)&op[(size_t)(c0 + j) * R + r0 + k0] = w;
  }
}

// ----- 128x256x32 grouped GEMM, 8 waves, wave-out 64x64 (R11 schedule) -----
// 8 waves (2M x 4N), acc[4][4]=64 VGPR, BK=32 (64 rounds), double-buffered
// LDS 48KB (A 8KB + B 16KB per buf) -> 2 blk/CU = 16 waves. Operand cap:
// reads 8w*8*12 + 192 = 960 cyc vs MFMA 621 -> 65% (R11: 48%). Per round:
// stageA(kt+1) [1 vm] -> bf reads [4 b128] -> window-1 (mi 0,1) -> BARRIER ->
// stageB(s, kt+2) [2 vm, same-parity] -> window-2 (mi 2,3) -> VMCNT(2)
// (drains B(kt+1)+A(kt+1), keeps B(kt+2)) -> BARRIER.
// Swizzle (BK=32): chunk' = fhi ^ ((r>>1)&3) -- R4-measured 2-way-free;
// inverse applied at the global source (LDS dest linear).
// Dispatch remap: XCD group (oid&7) owns an nt-subrange -> B strips L2-hot.
// G1: B rows 0-127 = gate cols (nt*128 strip), 128-255 = up cols; wave wn
//     owns 32 gate (ci 0,1) + 32 up (ci 2,3) -> in-wave exact gelu -> act.
// G0: B rows = 256 down cols (nt*256 strip); ct = wn*4+ci -> y.
template <int G1>
__global__ __launch_bounds__(512, 4) void k_gemm(
    const f16* __restrict__ Asrc, const f16* __restrict__ Bsrc,
    const int* __restrict__ slot_tok,
    const int* __restrict__ tile_e, const int* __restrict__ tile_r0,
    const int* __restrict__ n_tiles, f16* __restrict__ dst) {
  __shared__ __align__(16) f16 smem[2][12288];  // per buf: A[0,4096) B[4096,12288)

  // XCD-grouped remap: group (oid&7) owns an nt-subrange across all m-tiles
  const int NTX = G1 ? 16 : 8;
  const int GP = NTX / 8;
  const int oid = (int)(blockIdx.y * NTX + blockIdx.x);
  const int nt = (oid & 7) * GP + ((oid >> 3) & (GP - 1));
  const int bx = oid >> (G1 ? 4 : 3);
  if (bx >= *n_tiles) return;
  const int e = tile_e[bx];
  const int m0 = tile_r0[bx];

  const int tid = threadIdx.x;
  const int lane = tid & 63;
  const int wv = tid >> 6;
  const int wrM = wv >> 2;   // 0..1 : 64-row band
  const int wn = wv & 3;     // 0..3 : 64-col group
  const int fr = lane & 15;
  const int fhi = lane >> 4;

  // ---- A staging: 1 gload_lds, row tid>>2 (0..127), chunk tid&3 ----
  const int ar = tid >> 2;
  const int asc = (tid & 3) ^ ((ar >> 1) & 3);
  size_t arow0 = G1 ? (size_t)slot_tok[m0 + ar] : (size_t)(m0 + ar);
  const f16* aS = Asrc + arow0 * 2048 + asc * 8;
  auto stageA = [&](int s, int kt) {
    gload_lds16(aS + (size_t)kt * 32, &smem[s][tid * 8]);
  };

  // ---- B staging: 2 gload_lds; instr i covers B-rows i*128 + (tid>>2) ----
  const f16* bS[2];
#pragma unroll
  for (int i = 0; i < 2; ++i) {
    const int rl = i * 128 + (tid >> 2);        // B LDS row 0..255
    const int sc = (tid & 3) ^ ((rl >> 1) & 3);
    size_t brow;
    if (G1) brow = (size_t)e * 4096 + (rl < 128 ? (size_t)(nt * 128 + rl)
                                                : (size_t)(2048 + nt * 128 + rl - 128));
    else    brow = (size_t)e * 2048 + nt * 256 + rl;
    bS[i] = Bsrc + brow * 2048 + sc * 8;
  }
  auto stageB = [&](int s, int kt) {
#pragma unroll
    for (int i = 0; i < 2; ++i)
      gload_lds16(bS[i] + (size_t)kt * 32, &smem[s][4096 + i * 4096 + tid * 8]);
  };

  // B-frag col-tiles (16-row units of the 256-row B region)
  int ctv[4];
#pragma unroll
  for (int ci = 0; ci < 4; ++ci) {
    if (G1) ctv[ci] = (ci < 2) ? (wn * 2 + ci) : (8 + wn * 2 + (ci - 2));
    else    ctv[ci] = wn * 4 + ci;
  }

  f32x4 acc[4][4];
#pragma unroll
  for (int i = 0; i < 4; ++i)
#pragma unroll
    for (int j = 0; j < 4; ++j) acc[i][j] = (f32x4){0.f, 0.f, 0.f, 0.f};

  const int NT = 64;  // K / 32

  // prologue: B(0):2, A(0):1, B(1):2 -> VMCNT(2) keeps B(1) in flight
  stageB(0, 0);
  stageA(0, 0);
  stageB(1, 1);
  VMCNT(2);
  BARRIER();

  for (int kt = 0; kt < NT; ++kt) {
    const int s = kt & 1;
    if (kt + 1 < NT) stageA(s ^ 1, kt + 1);  // 1 vm

    const f16* As = &smem[s][0];
    const f16* Bs = &smem[s][4096];
    f16x8 bf[4];
#pragma unroll
    for (int ci = 0; ci < 4; ++ci) {
      const int c = ctv[ci] * 16 + fr;
      bf[ci] = *(const f16x8*)&Bs[c * 32 + ((fhi ^ ((c >> 1) & 3)) << 3)];
    }
    // window 1: mi 0,1 (all B consumed into regs before mid-barrier)
#pragma unroll
    for (int mi = 0; mi < 2; ++mi) {
      const int r = wrM * 64 + mi * 16 + fr;
      const f16x8 af = *(const f16x8*)&As[r * 32 + ((fhi ^ ((r >> 1) & 3)) << 3)];
      __builtin_amdgcn_s_setprio(1);
#pragma unroll
      for (int ci = 0; ci < 4; ++ci)
        acc[mi][ci] = __builtin_amdgcn_mfma_f32_16x16x32_f16(af, bf[ci],
                                                             acc[mi][ci], 0, 0, 0);
      __builtin_amdgcn_s_setprio(0);
    }
    BARRIER();  // all waves' B(kt) reads done -> B region reusable
    if (kt + 2 < NT) stageB(s, kt + 2);  // same-parity B buffer, 2 vm
    // window 2: mi 2,3
#pragma unroll
    for (int mi = 2; mi < 4; ++mi) {
      const int r = wrM * 64 + mi * 16 + fr;
      const f16x8 af = *(const f16x8*)&As[r * 32 + ((fhi ^ ((r >> 1) & 3)) << 3)];
      __builtin_amdgcn_s_setprio(1);
#pragma unroll
      for (int ci = 0; ci < 4; ++ci)
        acc[mi][ci] = __builtin_amdgcn_mfma_f32_16x16x32_f16(af, bf[ci],
                                                             acc[mi][ci], 0, 0, 0);
      __builtin_amdgcn_s_setprio(0);
    }
    // boundary: drain A(kt+1)+B(kt+1), keep B(kt+2) in flight
    if (kt + 1 < NT) {
      if (kt + 2 < NT) { VMCNT(2); } else { VMCNT(0); }
      BARRIER();
    }
  }

  // ---- epilogue (no LDS) ----
  if (G1) {
#pragma unroll
    for (int mi = 0; mi < 4; ++mi)
#pragma unroll
      for (int ci = 0; ci < 2; ++ci)
#pragma unroll
        for (int rg = 0; rg < 4; ++rg) {
          const int row = m0 + wrM * 64 + mi * 16 + fhi * 4 + rg;
          const int col = nt * 128 + (wn * 2 + ci) * 16 + fr;
          const float g = acc[mi][ci][rg];
          const float u = acc[mi][ci + 2][rg];
          const float a = 0.5f * g * (1.0f + erff(g * 0.70710678118654752f)) * u;
          dst[(size_t)row * 2048 + col] = (f16)a;
        }
  } else {
#pragma unroll
    for (int mi = 0; mi < 4; ++mi)
#pragma unroll
      for (int ci = 0; ci < 4; ++ci)
#pragma unroll
        for (int rg = 0; rg < 4; ++rg) {
          const int row = m0 + wrM * 64 + mi * 16 + fhi * 4 + rg;
          const int col = nt * 256 + (wn * 4 + ci) * 16 + fr;
          dst[(size_t)row * 2048 + col] = (f16)acc[mi][ci][rg];
        }
  }
}

// out[tok] = w(s0)*y[s0] + w(s1)*y[s1]  (fully writes out; no memset needed)
__global__ void k_combine(const f16* __restrict__ y, const float* __restrict__ slot_w,
                          const int* __restrict__ tok_slot, float* __restrict__ out) {
  const int gid = blockIdx.x * blockDim.x + threadIdx.x;
  const int tok = gid >> 8;
  const int c = (gid & 255) * 8;
  const int s0 = tok_slot[2 * tok], s1 = tok_slot[2 * tok + 1];
  const float w0 = slot_w[s0], w1 = slot_w[s1];
  const f16x8 v0 = *(const f16x8*)&y[(size_t)s0 * 2048 + c];
  const f16x8 v1 = *(const f16x8*)&y[(size_t)s1 * 2048 + c];
  float o[8];
#pragma unroll
  for (int j = 0; j < 8; ++j) o[j] = w0 * (float)v0[j] + w1 * (float)v1[j];
  float4* op = (float4*)&out[(size_t)tok * 2048 + c];
  op[0] = (float4){o[0], o[1], o[2], o[3]};
  op[1] = (float4){o[4], o[5], o[6], o[7]};
}

extern "C" void kernel_launch(void* const* d_in, const int* in_sizes, int n_in,
                              void* d_out, int out_size, void* d_ws, size_t ws_size,
                              hipStream_t stream) {
  const float* x = (const float*)d_in[0];
  const float* wts = (const float*)d_in[1];
  const int* idx = (const int*)d_in[2];
  const float* gup = (const float*)d_in[3];
  const float* dwn = (const float*)d_in[4];
  const float* scale = (const float*)d_in[5];
  float* out = (float*)d_out;

  char* ws = (char*)d_ws;
  f16* gup_t = (f16*)(ws + GUPT_OFF);
  f16* y = (f16*)(ws + Y_OFF);          // aliases gup_t (dead after GEMM1)
  f16* down_t = (f16*)(ws + DWNT_OFF);  // aliases gup_t tail (dead after GEMM1)
  f16* xf = (f16*)(ws + XF_OFF);
  f16* act = (f16*)(ws + ACT_OFF);
  int* ctrl = (int*)(ws + CTRL_OFF);
  int* slot_tok = ctrl;
  int* tok_slot = ctrl + 9216;
  int* cnt = ctrl + 17408;
  int* cursor = ctrl + 17416;
  int* tile_e = ctrl + 17424;
  int* tile_r0 = ctrl + 17496;
  int* n_tiles = ctrl + 17568;
  int* is32 = ctrl + 17569;
  float* slot_w = (float*)(ctrl + 17576);

  hipMemsetAsync(ctrl, 0, (size_t)CTRL_INTS * sizeof(int), stream);

  k_detect<<<NPAIR / 2 / 256, 256, 0, stream>>>(idx, is32);
  k_count<<<NPAIR / 256, 256, 0, stream>>>(idx, is32, cnt);
  k_plan<<<1, 1, 0, stream>>>(cnt, cursor, tile_e, tile_r0, n_tiles);
  k_assign<<<NPAIR / 256, 256, 0, stream>>>(idx, is32, wts, scale, cursor,
                                            slot_tok, tok_slot, slot_w);
  k_cvt_x<<<NTOK * DDIM / 4 / 256, 256, 0, stream>>>(x, xf);
  k_transpose<<<dim3(4096 / 64, 2048 / 64, EXPERTS), 256, 0, stream>>>(
      gup, gup_t, 2048, 4096);
  k_gemm<1><<<dim3(16, MAXTILE), 512, 0, stream>>>(xf, gup_t, slot_tok, tile_e,
                                                   tile_r0, n_tiles, act);
  // gup_t dead now; transpose down into its tail, y into its head
  k_transpose<<<dim3(2048 / 64, 2048 / 64, EXPERTS), 256, 0, stream>>>(
      dwn, down_t, 2048, 2048);
  k_gemm<0><<<dim3(8, MAXTILE), 512, 0, stream>>>(act, down_t, slot_tok, tile_e,
                                                  tile_r0, n_tiles, y);
  k_combine<<<NTOK, 256, 0, stream>>>(y, slot_w, tok_slot, out);
}

// Round 15
// 461.860 us; speedup vs baseline: 1.3249x; 1.0446x over previous
//
#include <hip/hip_runtime.h>
#include <math.h>

// Problem constants
#define EXPERTS 8
#define DDIM 2048
#define HDIM 2048
#define NTOK 4096
#define NPAIR 8192
#define MAXSLOT 9216    // 8192 + 8*127 rounded up (128-padded per expert)
#define MAXTILE 72      // max sum of ceil(cnt_e/128)

typedef _Float16 f16;
typedef __attribute__((ext_vector_type(8))) _Float16 f16x8;
typedef __attribute__((ext_vector_type(4))) _Float16 f16x4;
typedef __attribute__((ext_vector_type(4))) float f32x4;

// ---- workspace layout (bytes); peak ~193 MB (R2-proven aliasing) ----
// Phase 1: gup_t f16 [E][4096][2048] @0 (128MB)
// Phase 2 (gup_t dead after GEMM1): y @0 (37.75MB), down_t @41.94MB (64MB)
#define GUPT_OFF 0ull
#define Y_OFF    0ull
#define DWNT_OFF 41943040ull
#define XF_OFF   134217728ull    // f16 [NTOK][2048] = 16MB
#define ACT_OFF  150994944ull    // f16 [MAXSLOT][2048] = 37.75MB
#define CTRL_OFF 192937984ull
// ctrl ints: slot_tok[9216]@0, tok_slot[8192]@9216, cnt[8]@17408,
// cursor[8]@17416, tile_e[72]@17424, tile_r0[72]@17496, n_tiles@17568,
// is32@17569, slot_w(float)[9216]@17576
#define CTRL_INTS 26792

#define BARRIER() asm volatile("s_barrier" ::: "memory")
#define VMCNT(n)  asm volatile("s_waitcnt vmcnt(" #n ")" ::: "memory")

__device__ __forceinline__ void gload_lds16(const void* g, void* l) {
  __builtin_amdgcn_global_load_lds(
      (const __attribute__((address_space(1))) unsigned int*)g,
      (__attribute__((address_space(3))) unsigned int*)l,
      16, 0, 0);
}

// ---------------- routing ----------------
__global__ void k_detect(const int* __restrict__ w, int* flag) {
  int i = blockIdx.x * blockDim.x + threadIdx.x;
  if (i < NPAIR / 2 && w[2 * i + 1] != 0) atomicOr(flag, 1);
}

__device__ __forceinline__ int expert_of(const int* idx, int is32, int p) {
  return is32 ? idx[p] : idx[2 * p];
}

__global__ void k_count(const int* __restrict__ idx, const int* __restrict__ flag,
                        int* cnt) {
  int p = blockIdx.x * blockDim.x + threadIdx.x;
  if (p < NPAIR) atomicAdd(&cnt[expert_of(idx, *flag, p)], 1);
}

__global__ void k_plan(const int* __restrict__ cnt, int* cursor,
                       int* tile_e, int* tile_r0, int* n_tiles) {
  if (blockIdx.x == 0 && threadIdx.x == 0) {
    int off = 0, nt = 0;
    for (int e = 0; e < EXPERTS; ++e) {
      cursor[e] = off;
      int t = (cnt[e] + 127) >> 7;
      for (int i = 0; i < t; ++i) { tile_e[nt] = e; tile_r0[nt] = off + i * 128; ++nt; }
      off += t * 128;
    }
    *n_tiles = nt;
  }
}

__global__ void k_assign(const int* __restrict__ idx, const int* __restrict__ flag,
                         const float* __restrict__ wts, const float* __restrict__ scale,
                         int* cursor, int* slot_tok, int* tok_slot, float* slot_w) {
  int p = blockIdx.x * blockDim.x + threadIdx.x;
  if (p < NPAIR) {
    int e = expert_of(idx, *flag, p);
    int pos = atomicAdd(&cursor[e], 1);
    slot_tok[pos] = p >> 1;
    tok_slot[p] = pos;
    slot_w[pos] = wts[p] * scale[e];
  }
}

__global__ void k_cvt_x(const float* __restrict__ in, f16* __restrict__ out) {
  int i = blockIdx.x * blockDim.x + threadIdx.x;
  float4 v = ((const float4*)in)[i];
  f16x4 o = {(f16)v.x, (f16)v.y, (f16)v.z, (f16)v.w};
  ((f16x4*)out)[i] = o;
}

// ---- fast fused cvt+transpose: f32 [R][C] -> f16 [C][R], per expert z ----
__global__ __launch_bounds__(256) void k_transpose(const float* __restrict__ in,
                                                   f16* __restrict__ out,
                                                   int R, int C) {
  __shared__ float t[64][65];
  const size_t base = (size_t)blockIdx.z * R * C;
  const float* ip = in + base;
  f16* op = out + base;
  const int c0 = blockIdx.x * 64, r0 = blockIdx.y * 64;
  const int tid = threadIdx.x;
  const int rr = tid >> 4, cc = (tid & 15) * 4;
#pragma unroll
  for (int i = 0; i < 4; ++i) {
    float4 v = *(const float4*)&ip[(size_t)(r0 + rr + i * 16) * C + c0 + cc];
    *(float4*)&t[rr + i * 16][cc] = v;
  }
  __syncthreads();
  const int k0 = (tid & 7) * 8;
#pragma unroll
  for (int p = 0; p < 2; ++p) {
    const int j = (tid >> 3) + p * 32;
    f16x8 w = {(f16)t[k0 + 0][j], (f16)t[k0 + 1][j], (f16)t[k0 + 2][j],
               (f16)t[k0 + 3][j], (f16)t[k0 + 4][j], (f16)t[k0 + 5][j],
               (f16)t[k0 + 6][j], (f16)t[k0 + 7][j]};
    *(f16x8*)&op[(size_t)(c0 + j) * R + r0 + k0] = w;
  }
}

// -------- 128x128x64 grouped GEMM (R3 loop + R10 mapping), f16 both --------
// 8 waves (2M x 4N), wave-out 64x16-per-ci, acc[4][2]=32 VGPR, BK=64,
// double-buffered 64KB LDS -> 2 blk/CU. Per round: stageA(kt+1) -> B-frag
// reads -> window-1 (mi 0,1) -> BARRIER -> stageB(kt+2, same parity) ->
// window-2 (mi 2,3) -> VMCNT(2) (drains A(kt+1)+B(kt+1), keeps B(kt+2)) ->
// BARRIER. All operands via gload_lds (linear dest, source-swizzled).
// Dispatch remap: each XCD owns a fixed nt-group for all m-tiles -> B strips
// (<=2MB) L2-resident with ~9x reuse.
// G1: A = gathered xf; B = gup_t rows [64 gate | 64 up] for strip nt;
//     ci=0 gate ct=wcl, ci=1 up ct=4+wcl -> in-wave exact gelu -> act.
// G0: A = act; B = down_t 128-row strip -> y.
template <int G1>
__global__ __launch_bounds__(512, 2) void k_gemm(
    const f16* __restrict__ Asrc, const f16* __restrict__ Bsrc,
    const int* __restrict__ slot_tok,
    const int* __restrict__ tile_e, const int* __restrict__ tile_r0,
    const int* __restrict__ n_tiles, f16* __restrict__ dst) {
  __shared__ __align__(16) f16 smem[2][16384];  // per buf: A[0,8192) B[8192,16384)

  // XCD-clustered remap: group oid&7 owns an nt-subrange across all m-tiles
  const int NTX = G1 ? 32 : 16;        // nt tiles
  const int GP = NTX / 8;              // nt per XCD group
  const int oid = (int)(blockIdx.y * NTX + blockIdx.x);
  const int nt = (oid & 7) * GP + ((oid >> 3) & (GP - 1));
  const int bx = oid >> (G1 ? 5 : 4);
  if (bx >= *n_tiles) return;
  const int e = tile_e[bx];
  const int m0 = tile_r0[bx];

  const int tid = threadIdx.x;
  const int lane = tid & 63;
  const int wv = tid >> 6;
  const int wrM = wv >> 2;   // 0..1 : 64-row band
  const int wcl = wv & 3;    // 0..3 : 16-col tile group
  const int fr = lane & 15;
  const int fhi = lane >> 4;

  // staging sources (linear LDS dest, inverse-swizzled source chunk)
  const int sr = tid >> 3;                    // staging row 0..63 (per i: +64i)
  const int sc = (tid & 7) ^ (sr & 7);        // swizzle key (64 ≡ 0 mod 8)
  const f16* aS[2];
  const f16* bS[2];
#pragma unroll
  for (int i = 0; i < 2; ++i) {
    const int r = i * 64 + sr;
    size_t arow = G1 ? (size_t)slot_tok[m0 + r] : (size_t)(m0 + r);
    aS[i] = Asrc + arow * 2048 + sc * 8;
    size_t brow;
    if (G1) brow = (size_t)e * 4096 + (i ? (size_t)(2048 + nt * 64 + sr)
                                         : (size_t)(nt * 64 + sr));
    else    brow = (size_t)e * 2048 + nt * 128 + r;
    bS[i] = Bsrc + brow * 2048 + sc * 8;
  }
  auto stageA = [&](int s, int kt) {
#pragma unroll
    for (int i = 0; i < 2; ++i)
      gload_lds16(aS[i] + (size_t)kt * 64, &smem[s][i * 4096 + tid * 8]);
  };
  auto stageB = [&](int s, int kt) {
#pragma unroll
    for (int i = 0; i < 2; ++i)
      gload_lds16(bS[i] + (size_t)kt * 64, &smem[s][8192 + i * 4096 + tid * 8]);
  };

  // B-frag col-tiles: ci=0 gate ct=wcl, ci=1 up ct=wcl+4; G0: wcl*2+ci
  int ctv[2];
#pragma unroll
  for (int ci = 0; ci < 2; ++ci)
    ctv[ci] = G1 ? (wcl + ci * 4) : (wcl * 2 + ci);

  f32x4 acc[4][2];
#pragma unroll
  for (int i = 0; i < 4; ++i)
#pragma unroll
    for (int j = 0; j < 2; ++j) acc[i][j] = (f32x4){0.f, 0.f, 0.f, 0.f};

  const int NT = 32;  // K / 64

  // prologue: B(0):2, A(0):2, B(1):2 -> vmcnt(2) keeps B(1) in flight
  stageB(0, 0);
  stageA(0, 0);
  stageB(1, 1);
  VMCNT(2);
  BARRIER();

  for (int kt = 0; kt < NT; ++kt) {
    const int s = kt & 1;
    if (kt + 1 < NT) stageA(s ^ 1, kt + 1);  // 2 vm

    const f16* As = &smem[s][0];
    const f16* Bs = &smem[s][8192];
    f16x8 bf[2][2];
#pragma unroll
    for (int ci = 0; ci < 2; ++ci)
#pragma unroll
      for (int k0 = 0; k0 < 2; ++k0) {
        const int c = ctv[ci] * 16 + fr;
        bf[ci][k0] = *(const f16x8*)&Bs[c * 64 + (((k0 * 4 + fhi) ^ (c & 7)) << 3)];
      }
    // window 1: mi 0,1 (B fully consumed into regs before mid-barrier)
#pragma unroll
    for (int mi = 0; mi < 2; ++mi) {
      f16x8 af[2];
#pragma unroll
      for (int k0 = 0; k0 < 2; ++k0) {
        const int r = wrM * 64 + mi * 16 + fr;
        af[k0] = *(const f16x8*)&As[r * 64 + (((k0 * 4 + fhi) ^ (r & 7)) << 3)];
      }
      __builtin_amdgcn_s_setprio(1);
#pragma unroll
      for (int ci = 0; ci < 2; ++ci)
#pragma unroll
        for (int k0 = 0; k0 < 2; ++k0)
          acc[mi][ci] = __builtin_amdgcn_mfma_f32_16x16x32_f16(
              af[k0], bf[ci][k0], acc[mi][ci], 0, 0, 0);
      __builtin_amdgcn_s_setprio(0);
    }
    BARRIER();  // all waves' B(kt) reads in regs -> B region reusable
    if (kt + 2 < NT) stageB(s, kt + 2);  // same-parity B buffer, 2 vm
    // window 2: mi 2,3
#pragma unroll
    for (int mi = 2; mi < 4; ++mi) {
      f16x8 af[2];
#pragma unroll
      for (int k0 = 0; k0 < 2; ++k0) {
        const int r = wrM * 64 + mi * 16 + fr;
        af[k0] = *(const f16x8*)&As[r * 64 + (((k0 * 4 + fhi) ^ (r & 7)) << 3)];
      }
      __builtin_amdgcn_s_setprio(1);
#pragma unroll
      for (int ci = 0; ci < 2; ++ci)
#pragma unroll
        for (int k0 = 0; k0 < 2; ++k0)
          acc[mi][ci] = __builtin_amdgcn_mfma_f32_16x16x32_f16(
              af[k0], bf[ci][k0], acc[mi][ci], 0, 0, 0);
      __builtin_amdgcn_s_setprio(0);
    }
    // boundary: drain A(kt+1)+B(kt+1), keep B(kt+2) in flight
    if (kt + 1 < NT) {
      if (kt + 2 < NT) { VMCNT(2); } else { VMCNT(0); }
      BARRIER();
    }
  }

  // ---- epilogue (no LDS) ----
  if (G1) {
#pragma unroll
    for (int mi = 0; mi < 4; ++mi)
#pragma unroll
      for (int rg = 0; rg < 4; ++rg) {
        const int row = m0 + wrM * 64 + mi * 16 + fhi * 4 + rg;
        const int col = nt * 64 + wcl * 16 + fr;
        const float g = acc[mi][0][rg];
        const float u = acc[mi][1][rg];
        const float a = 0.5f * g * (1.0f + erff(g * 0.70710678118654752f)) * u;
        dst[(size_t)row * 2048 + col] = (f16)a;
      }
  } else {
#pragma unroll
    for (int mi = 0; mi < 4; ++mi)
#pragma unroll
      for (int ci = 0; ci < 2; ++ci)
#pragma unroll
        for (int rg = 0; rg < 4; ++rg) {
          const int row = m0 + wrM * 64 + mi * 16 + fhi * 4 + rg;
          const int col = nt * 128 + (wcl * 2 + ci) * 16 + fr;
          dst[(size_t)row * 2048 + col] = (f16)acc[mi][ci][rg];
        }
  }
}

// out[tok] = w(s0)*y[s0] + w(s1)*y[s1]  (fully writes out; no memset needed)
__global__ void k_combine(const f16* __restrict__ y, const float* __restrict__ slot_w,
                          const int* __restrict__ tok_slot, float* __restrict__ out) {
  const int gid = blockIdx.x * blockDim.x + threadIdx.x;
  const int tok = gid >> 8;
  const int c = (gid & 255) * 8;
  const int s0 = tok_slot[2 * tok], s1 = tok_slot[2 * tok + 1];
  const float w0 = slot_w[s0], w1 = slot_w[s1];
  const f16x8 v0 = *(const f16x8*)&y[(size_t)s0 * 2048 + c];
  const f16x8 v1 = *(const f16x8*)&y[(size_t)s1 * 2048 + c];
  float o[8];
#pragma unroll
  for (int j = 0; j < 8; ++j) o[j] = w0 * (float)v0[j] + w1 * (float)v1[j];
  float4* op = (float4*)&out[(size_t)tok * 2048 + c];
  op[0] = (float4){o[0], o[1], o[2], o[3]};
  op[1] = (float4){o[4], o[5], o[6], o[7]};
}

extern "C" void kernel_launch(void* const* d_in, const int* in_sizes, int n_in,
                              void* d_out, int out_size, void* d_ws, size_t ws_size,
                              hipStream_t stream) {
  const float* x = (const float*)d_in[0];
  const float* wts = (const float*)d_in[1];
  const int* idx = (const int*)d_in[2];
  const float* gup = (const float*)d_in[3];
  const float* dwn = (const float*)d_in[4];
  const float* scale = (const float*)d_in[5];
  float* out = (float*)d_out;

  char* ws = (char*)d_ws;
  f16* gup_t = (f16*)(ws + GUPT_OFF);
  f16* y = (f16*)(ws + Y_OFF);          // aliases gup_t (dead after GEMM1)
  f16* down_t = (f16*)(ws + DWNT_OFF);  // aliases gup_t tail (dead after GEMM1)
  f16* xf = (f16*)(ws + XF_OFF);
  f16* act = (f16*)(ws + ACT_OFF);
  int* ctrl = (int*)(ws + CTRL_OFF);
  int* slot_tok = ctrl;
  int* tok_slot = ctrl + 9216;
  int* cnt = ctrl + 17408;
  int* cursor = ctrl + 17416;
  int* tile_e = ctrl + 17424;
  int* tile_r0 = ctrl + 17496;
  int* n_tiles = ctrl + 17568;
  int* is32 = ctrl + 17569;
  float* slot_w = (float*)(ctrl + 17576);

  hipMemsetAsync(ctrl, 0, (size_t)CTRL_INTS * sizeof(int), stream);

  k_detect<<<NPAIR / 2 / 256, 256, 0, stream>>>(idx, is32);
  k_count<<<NPAIR / 256, 256, 0, stream>>>(idx, is32, cnt);
  k_plan<<<1, 1, 0, stream>>>(cnt, cursor, tile_e, tile_r0, n_tiles);
  k_assign<<<NPAIR / 256, 256, 0, stream>>>(idx, is32, wts, scale, cursor,
                                            slot_tok, tok_slot, slot_w);
  k_cvt_x<<<NTOK * DDIM / 4 / 256, 256, 0, stream>>>(x, xf);
  k_transpose<<<dim3(4096 / 64, 2048 / 64, EXPERTS), 256, 0, stream>>>(
      gup, gup_t, 2048, 4096);
  k_gemm<1><<<dim3(32, MAXTILE), 512, 0, stream>>>(xf, gup_t, slot_tok, tile_e,
                                                   tile_r0, n_tiles, act);
  // gup_t dead now; transpose down into its tail, y into its head
  k_transpose<<<dim3(2048 / 64, 2048 / 64, EXPERTS), 256, 0, stream>>>(
      dwn, down_t, 2048, 2048);
  k_gemm<0><<<dim3(16, MAXTILE), 512, 0, stream>>>(act, down_t, slot_tok, tile_e,
                                                   tile_r0, n_tiles, y);
  k_combine<<<NTOK, 256, 0, stream>>>(y, slot_w, tok_slot, out);
}